// Round 1
// 431.475 us; speedup vs baseline: 1.1870x; 1.1870x over previous
//
#include <hip/hip_runtime.h>
#include <hip/hip_bf16.h>

using f16 = _Float16;
typedef __attribute__((ext_vector_type(8))) f16 half8;
typedef __attribute__((ext_vector_type(4))) f16 half4;
typedef __attribute__((ext_vector_type(4))) float floatx4;

#define LN_EPS 1e-5f

// ---------------------------------------------------------------------------
// async global->LDS, 16B per lane. LDS dest is wave-uniform base + lane*16.
// ---------------------------------------------------------------------------
__device__ __forceinline__ void gload_lds16(const f16* g, f16* l) {
  __builtin_amdgcn_global_load_lds(
      (const __attribute__((address_space(1))) void*)g,
      (__attribute__((address_space(3))) void*)l, 16, 0, 0);
}

#define CFENCE asm volatile("" ::: "memory")
#define WAIT_VM(N) asm volatile("s_waitcnt vmcnt(" #N ")" ::: "memory")
#define BARRIER()                    \
  do {                               \
    CFENCE;                          \
    __builtin_amdgcn_s_barrier();    \
    CFENCE;                          \
  } while (0)

// ---------------------------------------------------------------------------
// 128x128 GEMM core (m97 structure) -- kept for the small composite GEMMs.
// C[128x128 tile] = A[M,K]*B[Nc,K]^T, f16 in, fp32 accum. 256 thr (4 waves).
// ---------------------------------------------------------------------------
template <int EPI>
__device__ __forceinline__ void gemm_core(
    const f16* __restrict__ A, const f16* __restrict__ B,
    f16* __restrict__ Ch, const float* __restrict__ bias,
    int lda, int ldb, int ldc, int kper, int kbeg, int bm, int bn,
    f16* As, f16* Bs) {
  const int t = threadIdx.x;
  const int wave = t >> 6, lane = t & 63;
  const int wm = (wave >> 1) << 6;   // wave row offset (0/64)
  const int wn = (wave & 1) << 6;    // wave col offset (0/64)
  const int lrow = lane & 15;        // fragment m/n within 16
  const int lkc = lane >> 4;         // k-chunk 0..3

  floatx4 acc[4][4] = {};

  const int segr = lane >> 3;        // row within 8-row segment
  const int segc = (lane & 7) << 3;  // k offset 0..56
  const f16* Ag = A + (size_t)(bm + wave * 32 + segr) * lda + kbeg + segc;
  const f16* Bg = B + (size_t)(bn + wave * 32 + segr) * ldb + kbeg + segc;
  f16* AsW = As + wave * 4 * 512;    // wave-uniform segment bases
  f16* BsW = Bs + wave * 4 * 512;

  const f16* ApL = As + (wm + lrow) * 64 + lkc * 8;
  const f16* BpL = Bs + (wn + lrow) * 64 + lkc * 8;

  for (int kit = 0; kit < kper; kit += 64) {
#pragma unroll
    for (int l = 0; l < 4; ++l) {
      gload_lds16(Ag + (size_t)(l * 8) * lda, AsW + l * 512);
      gload_lds16(Bg + (size_t)(l * 8) * ldb, BsW + l * 512);
    }
    Ag += 64;
    Bg += 64;
    __syncthreads();
#pragma unroll
    for (int kk = 0; kk < 2; ++kk) {
      half8 af[4], bfr[4];
#pragma unroll
      for (int i = 0; i < 4; ++i)
        af[i] = *(const half8*)(ApL + kk * 32 + i * (16 * 64));
#pragma unroll
      for (int j = 0; j < 4; ++j)
        bfr[j] = *(const half8*)(BpL + kk * 32 + j * (16 * 64));
#pragma unroll
      for (int i = 0; i < 4; ++i)
#pragma unroll
        for (int j = 0; j < 4; ++j)
          acc[i][j] = __builtin_amdgcn_mfma_f32_16x16x32_f16(af[i], bfr[j],
                                                             acc[i][j], 0, 0, 0);
    }
    __syncthreads();
  }

  // C/D layout: col = lane&15, row = (lane>>4)*4 + reg  [m89/m91 verified]
  const int crow0 = bm + wm + lkc * 4;
  const int ccol0 = bn + wn + lrow;
#pragma unroll
  for (int i = 0; i < 4; ++i) {
#pragma unroll
    for (int r = 0; r < 4; ++r) {
      const size_t row = (size_t)(crow0 + i * 16 + r);
#pragma unroll
      for (int j = 0; j < 4; ++j) {
        const int col = ccol0 + j * 16;
        float v = acc[i][j][r];
        if (EPI == 2) v = fmaxf(v + bias[col], 0.0f);
        Ch[row * (size_t)ldc + col] = (f16)v;
      }
    }
  }
}

// ---------------------------------------------------------------------------
// 256x256-tile 8-phase pipelined GEMM (T1+T2+T3+T4+T5), 512 thr (8 waves,
// 2Mx4N), BK=64, per-wave output 128x64 (acc[8][4] f32x4), 128 KiB LDS
// (2 K-tile buffers x (A 256x64 + B 256x64) f16).
//
// Schedule per main iter (2 K-tiles: t0=2i -> buf0, t1=2i+1 -> buf1); each
// phase = [ds_read subtile | issue 1 half-tile global_load_lds | (vmcnt)]
//         BARRIER ; setprio(1) 16xMFMA setprio(0) ; BARRIER.
//   P0: LDA(q0)+LDB(q0)   stage t1.h1       MFMA Q(0,0)
//   P1: LDB(q1)           stage t1.h2       MFMA Q(0,1)
//   P2: LDA(q1)           stage t1.h3       MFMA Q(1,0)
//   P3:                   stage t2.h0  vmcnt(2)=t1 landed   MFMA Q(1,1)
//   P4..P6: same on t1,   stage t2.h1..h3
//   P7:                   stage t3.h0  vmcnt(2)=t2 landed   MFMA Q(1,1)
// Stages only target buffers whose reads completed before the previous
// trailing barrier (WAR-safe); vmcnt counts are exact (2 newer loads = the
// half-tile issued in the waiting phase). Last iter: no P3..P7 stages,
// vmcnt(0) at P3. Raw s_barrier (no compiler vmcnt(0) drain) + CFENCEs pin
// memory ops inside phases.
//
// LDS swizzle (T2): physical 16B chunk c' = c ^ (row&7). Staging keeps the
// LDS dest linear and pre-swizzles the per-lane GLOBAL source chunk
// ((lane&7)^(lane>>3)); fragment ds_read_b128 uses chunk (kk*4+lkc)^(lrow&7)
// -> 16 lanes of a bank-group spread over 8 slots (conflict-free).
// ---------------------------------------------------------------------------
template <int EPI>
__global__ __launch_bounds__(512, 2) void gemm256(
    const f16* __restrict__ A, const f16* __restrict__ B,
    f16* __restrict__ Ch, const float* __restrict__ bias,
    int M, int Nc, int K, int lda, int ldb, int ldc) {
  __shared__ f16 sm[4][256 * 64];  // [buf*2 + (0=A,1=B)][row*64 + k]

  // bijective XCD-chunked block swizzle (T1); all grids here have nwg=256
  const int gx = gridDim.x, gy = gridDim.y;
  const int nwg = gx * gy * gridDim.z;
  const int id = blockIdx.x + gx * (blockIdx.y + gy * blockIdx.z);
  const int q = nwg >> 3, r = nwg & 7;
  const int xcd = id & 7, lin = id >> 3;
  const int nid = (xcd < r ? xcd * (q + 1) : r * (q + 1) + (xcd - r) * q) + lin;
  const int bx = nid % gx;
  const int by = (nid / gx) % gy;
  const int bz = nid / (gx * gy);

  const int kper = K / gridDim.z;
  const int kbeg = bz * kper;
  f16* Cz = Ch + (size_t)bz * M * ldc;
  const int bm = by << 8, bn = bx << 8;

  const int t = threadIdx.x;
  const int wave = t >> 6, lane = t & 63;
  const int wm = (wave >> 2) << 7;  // wave M offset: 0/128
  const int wn = (wave & 3) << 6;   // wave N offset: 0/64/128/192
  const int lrow = lane & 15, lkc = lane >> 4;

  // staging: seg = wave*2+l covers 8 rows of a 128-row half-tile
  const int srow = lane >> 3;
  const int schunk = ((lane & 7) ^ srow) << 3;  // swizzled source chunk (elems)
  const f16* Ag = A + (size_t)(bm + wave * 16 + srow) * lda + kbeg + schunk;
  const f16* Bg = B + (size_t)(bn + wave * 16 + srow) * ldb + kbeg + schunk;

  // swizzled fragment k-offsets (elems within 64-elem row), kk = 0 / 1
  const int co0 = ((lkc ^ (lrow & 7)) << 3);
  const int co1 = (((4 + lkc) ^ (lrow & 7)) << 3);

  floatx4 acc[8][4] = {};
  half8 af[4][2];       // one qm-half of A frags, both kk
  half8 bf[2][2][2];    // [qn][fn][kk] -- both qn halves live

  auto STAGE = [&](int b, int tt, int h) {  // h: 0=A-lo 1=A-hi 2=B-lo 3=B-hi
    if (h < 2) {
      const f16* src = Ag + (size_t)(h * 128) * lda + tt * 64;
      f16* d = &sm[b * 2][h * 8192 + wave * 1024];
      gload_lds16(src, d);
      gload_lds16(src + (size_t)8 * lda, d + 512);
    } else {
      const f16* src = Bg + (size_t)((h - 2) * 128) * ldb + tt * 64;
      f16* d = &sm[b * 2 + 1][(h - 2) * 8192 + wave * 1024];
      gload_lds16(src, d);
      gload_lds16(src + (size_t)8 * ldb, d + 512);
    }
  };
  auto LDA = [&](int b, int qm) {
    const f16* base = &sm[b * 2][(wm + qm * 64 + lrow) * 64];
#pragma unroll
    for (int fm = 0; fm < 4; ++fm) {
      af[fm][0] = *(const half8*)(base + fm * (16 * 64) + co0);
      af[fm][1] = *(const half8*)(base + fm * (16 * 64) + co1);
    }
  };
  auto LDB = [&](int b, int qn) {
    const f16* base = &sm[b * 2 + 1][(wn + qn * 32 + lrow) * 64];
#pragma unroll
    for (int fn = 0; fn < 2; ++fn) {
      bf[qn][fn][0] = *(const half8*)(base + fn * (16 * 64) + co0);
      bf[qn][fn][1] = *(const half8*)(base + fn * (16 * 64) + co1);
    }
  };
  auto MFMAQ = [&](int qm, int qn) {
    __builtin_amdgcn_s_setprio(1);
#pragma unroll
    for (int kk = 0; kk < 2; ++kk)
#pragma unroll
      for (int fm = 0; fm < 4; ++fm)
#pragma unroll
        for (int fn = 0; fn < 2; ++fn)
          acc[qm * 4 + fm][qn * 2 + fn] =
              __builtin_amdgcn_mfma_f32_16x16x32_f16(
                  af[fm][kk], bf[qn][fn][kk], acc[qm * 4 + fm][qn * 2 + fn],
                  0, 0, 0);
    __builtin_amdgcn_s_setprio(0);
  };

  const int NT = kper >> 6;  // K-tiles (even for all call sites)
  const int NI = NT >> 1;

  // prologue: tile0 -> buf0 (4 halves), tile1 half0 -> buf1; wait tile0
  STAGE(0, 0, 0); STAGE(0, 0, 1); STAGE(0, 0, 2); STAGE(0, 0, 3);
  STAGE(1, 1, 0);
  WAIT_VM(2);
  BARRIER();

  for (int i = 0; i < NI; ++i) {
    const bool last = (i == NI - 1);
    const int tb = 2 * i;
    // P0 -- t0 Q(0,0)
    LDA(0, 0); LDB(0, 0); STAGE(1, tb + 1, 1);
    BARRIER(); MFMAQ(0, 0); BARRIER();
    // P1 -- t0 Q(0,1)
    LDB(0, 1); STAGE(1, tb + 1, 2);
    BARRIER(); MFMAQ(0, 1); BARRIER();
    // P2 -- t0 Q(1,0)
    LDA(0, 1); STAGE(1, tb + 1, 3);
    BARRIER(); MFMAQ(1, 0); BARRIER();
    // P3 -- t0 Q(1,1); guarantee tile t1 landed before P4 reads buf1
    if (!last) {
      STAGE(0, tb + 2, 0);
      WAIT_VM(2);
    } else {
      WAIT_VM(0);
    }
    BARRIER(); MFMAQ(1, 1); BARRIER();
    // P4 -- t1 Q(0,0)
    LDA(1, 0); LDB(1, 0);
    if (!last) STAGE(0, tb + 2, 1);
    BARRIER(); MFMAQ(0, 0); BARRIER();
    // P5 -- t1 Q(0,1)
    LDB(1, 1);
    if (!last) STAGE(0, tb + 2, 2);
    BARRIER(); MFMAQ(0, 1); BARRIER();
    // P6 -- t1 Q(1,0)
    LDA(1, 1);
    if (!last) STAGE(0, tb + 2, 3);
    BARRIER(); MFMAQ(1, 0); BARRIER();
    // P7 -- t1 Q(1,1); guarantee tile t0+2 landed before next P0 reads buf0
    if (!last) {
      STAGE(1, tb + 3, 0);
      WAIT_VM(2);
    }
    BARRIER(); MFMAQ(1, 1); BARRIER();
  }

  // epilogue: C/D col = lane&15, row = (lane>>4)*4 + reg
  const int crow0 = bm + wm + lkc * 4;
  const int ccol0 = bn + wn + lrow;
#pragma unroll
  for (int i = 0; i < 8; ++i) {
#pragma unroll
    for (int r2 = 0; r2 < 4; ++r2) {
      const size_t row = (size_t)(crow0 + i * 16 + r2);
#pragma unroll
      for (int j = 0; j < 4; ++j) {
        const int col = ccol0 + j * 16;
        float v = acc[i][j][r2];
        if (EPI == 2) v = fmaxf(v + bias[col], 0.0f);
        Cz[row * (size_t)ldc + col] = (f16)v;
      }
    }
  }
}

// ---------------------------------------------------------------------------
// merged weight precompose: grid (8,8,16). z<8: WqkT chunk = Wkb@Wqb^T (K=4096
// split 8); z>=8: WvoT chunk = WoT@Wvb^T. f16 partial slabs, D x D each.
// ---------------------------------------------------------------------------
__global__ __launch_bounds__(256) void gemm_pre(
    const f16* __restrict__ Wkb, const f16* __restrict__ Wqb,
    const f16* __restrict__ WoT, const f16* __restrict__ Wvb,
    f16* __restrict__ parQK, f16* __restrict__ parVO, int D, int H) {
  __shared__ f16 As[128 * 64];
  __shared__ f16 Bs[128 * 64];
  const int z = blockIdx.z, zz = z & 7;
  const f16* A = (z < 8) ? Wkb : WoT;
  const f16* B = (z < 8) ? Wqb : Wvb;
  f16* slab = ((z < 8) ? parQK : parVO) + (size_t)zz * D * D;
  gemm_core<1>(A, B, slab, nullptr, H, H, D, H / 8, zz * (H / 8),
               blockIdx.y << 7, blockIdx.x << 7, As, Bs);
}

// ---------------------------------------------------------------------------
// merged th/xvoT: grid (8,64). y<32: th = xb@WqkT^T [N,D] (bm=y,bn=x).
// y>=32: xvoT = WvoT@xb^T [D,N] (bm=x, bn=y-32).
// ---------------------------------------------------------------------------
__global__ __launch_bounds__(256) void gemm_dual(
    const f16* __restrict__ xb, const f16* __restrict__ WqkT,
    const f16* __restrict__ WvoT, f16* __restrict__ th,
    f16* __restrict__ xvoT, int N, int D) {
  __shared__ f16 As[128 * 64];
  __shared__ f16 Bs[128 * 64];
  const int y = blockIdx.y;
  if (y < 32)
    gemm_core<1>(xb, WqkT, th, nullptr, D, D, D, D, 0,
                 y << 7, blockIdx.x << 7, As, Bs);
  else
    gemm_core<1>(WvoT, xb, xvoT, nullptr, D, D, N, D, 0,
                 blockIdx.x << 7, (y - 32) << 7, As, Bs);
}

// ---------------------------------------------------------------------------
// fused input prep, grid (128, 32, 7), block (32, 8):
// z0: W1 -> W1T transpose; z1: Wo -> WoT; z2: W2 -> W2T
// z3: x -> xb convert; z4/5/6: Wq/Wk/Wv -> Wqb/Wkb/Wvb convert
// ---------------------------------------------------------------------------
__global__ void prep_inputs(const float* x, const float* Wq, const float* Wk,
                            const float* Wv, const float* W1, const float* Wo,
                            const float* W2, f16* xb, f16* Wqb, f16* Wkb,
                            f16* Wvb, f16* W1T, f16* WoT, f16* W2T) {
  const int z = blockIdx.z;
  const int tx = threadIdx.x, ty = threadIdx.y;
  if (z >= 3) {  // converts
    const int t = ty * 32 + tx;
    const float* in;
    f16* out;
    size_t row, col, C;
    if (z == 3) {
      in = x; out = xb; C = 1024;
      row = blockIdx.x * 32 + (t >> 3);
      col = blockIdx.y * 32 + (t & 7) * 4;
    } else {
      in = (z == 4) ? Wq : (z == 5) ? Wk : Wv;
      out = (z == 4) ? Wqb : (z == 5) ? Wkb : Wvb;
      C = 4096;
      row = blockIdx.y * 32 + (t >> 3);
      col = blockIdx.x * 32 + (t & 7) * 4;
    }
    const float4 f = *(const float4*)(in + row * C + col);
    f16* o = out + row * C + col;
    o[0] = (f16)f.x; o[1] = (f16)f.y; o[2] = (f16)f.z; o[3] = (f16)f.w;
    return;
  }
  const float* in;
  f16* out;
  int R, C, r0, c0;
  if (z == 0) {
    R = 1024; C = 4096;
    r0 = blockIdx.y * 32; c0 = blockIdx.x * 32;
    in = W1; out = W1T;
  } else {
    R = 4096; C = 1024;
    r0 = blockIdx.x * 32; c0 = blockIdx.y * 32;
    in = (z == 1) ? Wo : W2;
    out = (z == 1) ? WoT : W2T;
  }
  __shared__ float tile[32][33];
#pragma unroll
  for (int i = 0; i < 32; i += 8)
    tile[ty + i][tx] = in[(size_t)(r0 + ty + i) * C + (c0 + tx)];
  __syncthreads();
#pragma unroll
  for (int i = 0; i < 32; i += 8)
    out[(size_t)(c0 + ty + i) * R + (r0 + tx)] = (f16)tile[tx][ty + i];
}

// ---------------------------------------------------------------------------
// merged slab reduce: first n/1024 blocks sum 8 f16 slabs parQK -> WqkT,
// remaining blocks do parVO -> WvoT. n = D*D.
// ---------------------------------------------------------------------------
__global__ void reduce_dual(const f16* __restrict__ parQK,
                            const f16* __restrict__ parVO,
                            f16* __restrict__ WqkT, f16* __restrict__ WvoT,
                            int n) {
  const int half = gridDim.x >> 1;
  const bool second = blockIdx.x >= half;
  const f16* par = second ? parVO : parQK;
  f16* out = second ? WvoT : WqkT;
  const int b = second ? blockIdx.x - half : blockIdx.x;
  const int i = (b * 256 + threadIdx.x) * 4;
  float s0 = 0, s1 = 0, s2 = 0, s3 = 0;
#pragma unroll
  for (int z = 0; z < 8; ++z) {
    const half4 p = *(const half4*)(par + (size_t)z * n + i);
    s0 += (float)p[0]; s1 += (float)p[1]; s2 += (float)p[2]; s3 += (float)p[3];
  }
  half4 o = {(f16)s0, (f16)s1, (f16)s2, (f16)s3};
  *(half4*)(out + i) = o;
}

// ---------------------------------------------------------------------------
// row softmax: f16 S[row,:N] -> f16 P. One 256-thread block per row, N=4096.
// ---------------------------------------------------------------------------
__global__ void softmax_rows(const f16* __restrict__ S, f16* __restrict__ P,
                             int N) {
  const int row = blockIdx.x;
  const int t = threadIdx.x;
  const int lane = t & 63, wave = t >> 6;
  const f16* s = S + (size_t)row * N;
  const half8 a = *(const half8*)(s + t * 8);
  const half8 b = *(const half8*)(s + 2048 + t * 8);
  float v[16];
#pragma unroll
  for (int i = 0; i < 8; ++i) {
    v[i] = (float)a[i];
    v[8 + i] = (float)b[i];
  }
  float mx = -1e30f;
#pragma unroll
  for (int i = 0; i < 16; ++i) mx = fmaxf(mx, v[i]);
#pragma unroll
  for (int off = 32; off > 0; off >>= 1) mx = fmaxf(mx, __shfl_xor(mx, off));
  __shared__ float red[8];
  if (lane == 0) red[wave] = mx;
  __syncthreads();
  mx = fmaxf(fmaxf(red[0], red[1]), fmaxf(red[2], red[3]));
  float sum = 0.0f;
#pragma unroll
  for (int i = 0; i < 16; ++i) {
    v[i] = __expf(v[i] - mx);
    sum += v[i];
  }
#pragma unroll
  for (int off = 32; off > 0; off >>= 1) sum += __shfl_xor(sum, off);
  if (lane == 0) red[4 + wave] = sum;
  __syncthreads();
  const float inv = 1.0f / (red[4] + red[5] + red[6] + red[7]);
  f16* p = P + (size_t)row * N;
  half8 oa, ob;
#pragma unroll
  for (int i = 0; i < 8; ++i) {
    oa[i] = (f16)(v[i] * inv);
    ob[i] = (f16)(v[8 + i] * inv);
  }
  *(half8*)(p + t * 8) = oa;
  *(half8*)(p + 2048 + t * 8) = ob;
}

// ---------------------------------------------------------------------------
// fused residual + f16 split-K slab reduce + (optional bias) + LayerNorm.
// One block per row, D=1024. b = base of nchunks f16 slabs, stride cs elems.
// ---------------------------------------------------------------------------
__global__ void add_ln(const float* __restrict__ a, const f16* __restrict__ b,
                       int nchunks, size_t cs, const float* __restrict__ bias,
                       const float* __restrict__ g, const float* __restrict__ be,
                       float* __restrict__ outf, f16* __restrict__ outh, int D) {
  const int row = blockIdx.x;
  const int t = threadIdx.x;
  const int lane = t & 63, wave = t >> 6;
  const float4 av = *(const float4*)(a + (size_t)row * D + t * 4);
  float s[4] = {av.x, av.y, av.z, av.w};
  for (int c = 0; c < nchunks; ++c) {
    const half4 bv = *(const half4*)(b + c * cs + (size_t)row * D + t * 4);
    s[0] += (float)bv[0]; s[1] += (float)bv[1];
    s[2] += (float)bv[2]; s[3] += (float)bv[3];
  }
  if (bias != nullptr) {
    const float4 bb = *(const float4*)(bias + t * 4);
    s[0] += bb.x; s[1] += bb.y; s[2] += bb.z; s[3] += bb.w;
  }
  float sum = s[0] + s[1] + s[2] + s[3];
  float sq = s[0] * s[0] + s[1] * s[1] + s[2] * s[2] + s[3] * s[3];
#pragma unroll
  for (int off = 32; off > 0; off >>= 1) {
    sum += __shfl_xor(sum, off);
    sq += __shfl_xor(sq, off);
  }
  __shared__ float red[8];
  if (lane == 0) {
    red[wave] = sum;
    red[4 + wave] = sq;
  }
  __syncthreads();
  sum = red[0] + red[1] + red[2] + red[3];
  sq = red[4] + red[5] + red[6] + red[7];
  const float mu = sum / (float)D;
  const float rv = rsqrtf(sq / (float)D - mu * mu + LN_EPS);
  const float4 gv = *(const float4*)(g + t * 4);
  const float4 bev = *(const float4*)(be + t * 4);
  float y0 = (s[0] - mu) * rv * gv.x + bev.x;
  float y1 = (s[1] - mu) * rv * gv.y + bev.y;
  float y2 = (s[2] - mu) * rv * gv.z + bev.z;
  float y3 = (s[3] - mu) * rv * gv.w + bev.w;
  if (outf != nullptr) {
    float4 o = {y0, y1, y2, y3};
    *(float4*)(outf + (size_t)row * D + t * 4) = o;
  }
  if (outh != nullptr) {
    f16* ob = outh + (size_t)row * D + t * 4;
    ob[0] = (f16)y0;
    ob[1] = (f16)y1;
    ob[2] = (f16)y2;
    ob[3] = (f16)y3;
  }
}

// ---------------------------------------------------------------------------
// launch
// ---------------------------------------------------------------------------
extern "C" void kernel_launch(void* const* d_in, const int* in_sizes, int n_in,
                              void* d_out, int out_size, void* d_ws,
                              size_t ws_size, hipStream_t stream) {
  constexpr int N = 4096, D = 1024, H = 4096;
  const float* x = (const float*)d_in[0];
  const float* Wq = (const float*)d_in[1];
  const float* Wk = (const float*)d_in[2];
  const float* Wv = (const float*)d_in[3];
  const float* Wo = (const float*)d_in[4];
  const float* W1 = (const float*)d_in[5];
  const float* b1 = (const float*)d_in[6];
  const float* W2 = (const float*)d_in[7];
  const float* b2 = (const float*)d_in[8];
  const float* g1 = (const float*)d_in[9];
  const float* be1 = (const float*)d_in[10];
  const float* g2 = (const float*)d_in[11];
  const float* be2 = (const float*)d_in[12];
  float* out = (float*)d_out;

  const size_t MB = 1024ull * 1024ull;
  char* w = (char*)d_ws;
  // workspace layout (228 MB used; hazard-checked reuse; offsets in MB):
  f16* xb   = (f16*)(w + 0 * MB);     // 8   [N,D]
  f16* Wqb  = (f16*)(w + 8 * MB);     // 8   [D,H]
  f16* Wkb  = (f16*)(w + 16 * MB);    // 8   [D,H]
  f16* Wvb  = (f16*)(w + 24 * MB);    // 8   [D,H]
  f16* WoT  = (f16*)(w + 32 * MB);    // 8   [D,H]
  f16* W1T  = (f16*)(w + 40 * MB);    // 8   [H,D]
  f16* W2T  = (f16*)(w + 48 * MB);    // 8   [D,H]
  f16* WqkT = (f16*)(w + 56 * MB);    // 2   [D,D] = (Wq@Wk^T)^T
  f16* WvoT = (f16*)(w + 58 * MB);    // 2   [D,D] = (Wv@Wo)^T
  f16* th   = (f16*)(w + 60 * MB);    // 8   [N,D]; dead after S
  f16* xvoT = (f16*)(w + 68 * MB);    // 8   [D,N]
  f16* F1   = (f16*)(w + 76 * MB);    // 32  [N,H]
  f16* Sh   = (f16*)(w + 108 * MB);   // 32  [N,N] f16; dead after softmax
  f16* parA = (f16*)(w + 108 * MB);   // 4x8MB f16 slabs (over dead Sh)
  f16* Pb   = (f16*)(w + 140 * MB);   // 32  [N,N]; dead after attn
  float* hf = (float*)(w + 172 * MB); // 16  [N,D]
  f16* hb   = (f16*)(w + 188 * MB);   // 8   [N,D]
  f16* parQK = (f16*)(w + 196 * MB);  // 16 = 8x2MB f16 slabs; dead after reduce
  f16* parVO = (f16*)(w + 212 * MB);  // 16 = 8x2MB f16 slabs; dead after reduce

  // ---- input prep: 4 converts + 3 transposes, ONE dispatch ----
  prep_inputs<<<dim3(128, 32, 7), dim3(32, 8), 0, stream>>>(
      x, Wq, Wk, Wv, W1, Wo, W2, xb, Wqb, Wkb, Wvb, W1T, WoT, W2T);

  // ---- weight precomposition (both [D,D] composites, one dispatch) ----
  gemm_pre<<<dim3(D / 128, D / 128, 16), 256, 0, stream>>>(
      Wkb, Wqb, WoT, Wvb, parQK, parVO, D, H);
  reduce_dual<<<2 * (D * D) / 1024, 256, 0, stream>>>(parQK, parVO, WqkT,
                                                      WvoT, D * D);

  // ---- attention ----
  // th = xb@WqkT^T [N,D] and xvoT = WvoT@xb^T [D,N], one dispatch
  gemm_dual<<<dim3(8, 64), 256, 0, stream>>>(xb, WqkT, WvoT, th, xvoT, N, D);
  // S = th @ xb^T  [N,N] f16 logits (K=1024), 256^2 8-phase kernel
  gemm256<1><<<dim3(N / 256, N / 256, 1), 512, 0, stream>>>(
      th, xb, Sh, nullptr, N, N, D, D, D, N);
  softmax_rows<<<N, 256, 0, stream>>>(Sh, Pb, N);
  // attn partials = Pb @ xvoT^T  [N,D], split-K=4, f16 slabs (over dead Sh)
  gemm256<1><<<dim3(D / 256, N / 256, 4), 512, 0, stream>>>(
      Pb, xvoT, parA, nullptr, N, D, N, N, N, D);
  // h = LN(x + sum(attn partials))
  add_ln<<<N, 256, 0, stream>>>(x, parA, 4, (size_t)N * D, nullptr, g1, be1,
                                hf, hb, D);

  // ---- feed-forward ----
  // F1 = relu(hb @ W1T^T + b1)  [N,H] f16
  gemm256<2><<<dim3(H / 256, N / 256, 1), 512, 0, stream>>>(
      hb, W1T, F1, b1, N, H, D, D, D, H);
  // F2 partials = F1 @ W2T^T  [N,D], split-K=4, f16 slabs
  gemm256<1><<<dim3(D / 256, N / 256, 4), 512, 0, stream>>>(
      F1, W2T, parA, nullptr, N, D, H, H, H, D);
  // out = LN(hf + sum(F2 partials) + b2)
  add_ln<<<N, 256, 0, stream>>>(hf, parA, 4, (size_t)N * D, b2, g2, be2,
                                out, nullptr, D);
}

// Round 2
// 406.159 us; speedup vs baseline: 1.2610x; 1.0623x over previous
//
#include <hip/hip_runtime.h>
#include <hip/hip_bf16.h>

using f16 = _Float16;
typedef __attribute__((ext_vector_type(8))) f16 half8;
typedef __attribute__((ext_vector_type(4))) f16 half4;
typedef __attribute__((ext_vector_type(4))) float floatx4;

#define LN_EPS 1e-5f

// ---------------------------------------------------------------------------
// async global->LDS, 16B per lane. LDS dest is wave-uniform base + lane*16.
// ---------------------------------------------------------------------------
__device__ __forceinline__ void gload_lds16(const f16* g, f16* l) {
  __builtin_amdgcn_global_load_lds(
      (const __attribute__((address_space(1))) void*)g,
      (__attribute__((address_space(3))) void*)l, 16, 0, 0);
}

#define CFENCE asm volatile("" ::: "memory")
#define WAIT_VM(N) asm volatile("s_waitcnt vmcnt(" #N ")" ::: "memory")
#define BARRIER()                    \
  do {                               \
    CFENCE;                          \
    __builtin_amdgcn_s_barrier();    \
    CFENCE;                          \
  } while (0)

// ---------------------------------------------------------------------------
// 256x256-tile 8-phase pipelined GEMM core (T1+T2+T3+T4+T5), 512 thr
// (8 waves, 2Mx4N), BK=64, per-wave output 128x64 (acc[8][4] f32x4),
// 128 KiB LDS (2 K-tile buffers x (A 256x64 + B 256x64) f16).
// Schedule identical to the round-1 harness-verified kernel; refactored into
// a device function so multiple wrappers share it (parameter-only changes
// inherit the verification).
// ---------------------------------------------------------------------------
template <int EPI>
__device__ __forceinline__ void gemm256_core(
    const f16* __restrict__ A, const f16* __restrict__ B,
    f16* __restrict__ Cz, const float* __restrict__ bias,
    int lda, int ldb, int ldc, int kper, int kbeg, int bm, int bn,
    f16* smp) {
  const int t = threadIdx.x;
  const int wave = t >> 6, lane = t & 63;
  const int wm = (wave >> 2) << 7;  // wave M offset: 0/128
  const int wn = (wave & 3) << 6;   // wave N offset: 0/64/128/192
  const int lrow = lane & 15, lkc = lane >> 4;

  // staging: seg = wave*2+l covers 8 rows of a 128-row half-tile
  const int srow = lane >> 3;
  const int schunk = ((lane & 7) ^ srow) << 3;  // swizzled source chunk (elems)
  const f16* Ag = A + (size_t)(bm + wave * 16 + srow) * lda + kbeg + schunk;
  const f16* Bg = B + (size_t)(bn + wave * 16 + srow) * ldb + kbeg + schunk;

  // swizzled fragment k-offsets (elems within 64-elem row), kk = 0 / 1
  const int co0 = ((lkc ^ (lrow & 7)) << 3);
  const int co1 = (((4 + lkc) ^ (lrow & 7)) << 3);

  floatx4 acc[8][4] = {};
  half8 af[4][2];       // one qm-half of A frags, both kk
  half8 bf[2][2][2];    // [qn][fn][kk] -- both qn halves live

  auto STAGE = [&](int b, int tt, int h) {  // h: 0=A-lo 1=A-hi 2=B-lo 3=B-hi
    if (h < 2) {
      const f16* src = Ag + (size_t)(h * 128) * lda + tt * 64;
      f16* d = smp + (b * 2) * 16384 + h * 8192 + wave * 1024;
      gload_lds16(src, d);
      gload_lds16(src + (size_t)8 * lda, d + 512);
    } else {
      const f16* src = Bg + (size_t)((h - 2) * 128) * ldb + tt * 64;
      f16* d = smp + (b * 2 + 1) * 16384 + (h - 2) * 8192 + wave * 1024;
      gload_lds16(src, d);
      gload_lds16(src + (size_t)8 * ldb, d + 512);
    }
  };
  auto LDA = [&](int b, int qm) {
    const f16* base = smp + (b * 2) * 16384 + (wm + qm * 64 + lrow) * 64;
#pragma unroll
    for (int fm = 0; fm < 4; ++fm) {
      af[fm][0] = *(const half8*)(base + fm * (16 * 64) + co0);
      af[fm][1] = *(const half8*)(base + fm * (16 * 64) + co1);
    }
  };
  auto LDB = [&](int b, int qn) {
    const f16* base = smp + (b * 2 + 1) * 16384 + (wn + qn * 32 + lrow) * 64;
#pragma unroll
    for (int fn = 0; fn < 2; ++fn) {
      bf[qn][fn][0] = *(const half8*)(base + fn * (16 * 64) + co0);
      bf[qn][fn][1] = *(const half8*)(base + fn * (16 * 64) + co1);
    }
  };
  auto MFMAQ = [&](int qm, int qn) {
    __builtin_amdgcn_s_setprio(1);
#pragma unroll
    for (int kk = 0; kk < 2; ++kk)
#pragma unroll
      for (int fm = 0; fm < 4; ++fm)
#pragma unroll
        for (int fn = 0; fn < 2; ++fn)
          acc[qm * 4 + fm][qn * 2 + fn] =
              __builtin_amdgcn_mfma_f32_16x16x32_f16(
                  af[fm][kk], bf[qn][fn][kk], acc[qm * 4 + fm][qn * 2 + fn],
                  0, 0, 0);
    __builtin_amdgcn_s_setprio(0);
  };

  const int NT = kper >> 6;  // K-tiles (even for all call sites)
  const int NI = NT >> 1;

  // prologue: tile0 -> buf0 (4 halves), tile1 half0 -> buf1; wait tile0
  STAGE(0, 0, 0); STAGE(0, 0, 1); STAGE(0, 0, 2); STAGE(0, 0, 3);
  STAGE(1, 1, 0);
  WAIT_VM(2);
  BARRIER();

  for (int i = 0; i < NI; ++i) {
    const bool last = (i == NI - 1);
    const int tb = 2 * i;
    // P0 -- t0 Q(0,0)
    LDA(0, 0); LDB(0, 0); STAGE(1, tb + 1, 1);
    BARRIER(); MFMAQ(0, 0); BARRIER();
    // P1 -- t0 Q(0,1)
    LDB(0, 1); STAGE(1, tb + 1, 2);
    BARRIER(); MFMAQ(0, 1); BARRIER();
    // P2 -- t0 Q(1,0)
    LDA(0, 1); STAGE(1, tb + 1, 3);
    BARRIER(); MFMAQ(1, 0); BARRIER();
    // P3 -- t0 Q(1,1); guarantee tile t1 landed before P4 reads buf1
    if (!last) {
      STAGE(0, tb + 2, 0);
      WAIT_VM(2);
    } else {
      WAIT_VM(0);
    }
    BARRIER(); MFMAQ(1, 1); BARRIER();
    // P4 -- t1 Q(0,0)
    LDA(1, 0); LDB(1, 0);
    if (!last) STAGE(0, tb + 2, 1);
    BARRIER(); MFMAQ(0, 0); BARRIER();
    // P5 -- t1 Q(0,1)
    LDB(1, 1);
    if (!last) STAGE(0, tb + 2, 2);
    BARRIER(); MFMAQ(0, 1); BARRIER();
    // P6 -- t1 Q(1,0)
    LDA(1, 1);
    if (!last) STAGE(0, tb + 2, 3);
    BARRIER(); MFMAQ(1, 0); BARRIER();
    // P7 -- t1 Q(1,1); guarantee tile t0+2 landed before next P0 reads buf0
    if (!last) {
      STAGE(1, tb + 3, 0);
      WAIT_VM(2);
    }
    BARRIER(); MFMAQ(1, 1); BARRIER();
  }

  // epilogue: C/D col = lane&15, row = (lane>>4)*4 + reg
  const int crow0 = bm + wm + lkc * 4;
  const int ccol0 = bn + wn + lrow;
#pragma unroll
  for (int i = 0; i < 8; ++i) {
#pragma unroll
    for (int r2 = 0; r2 < 4; ++r2) {
      const size_t row = (size_t)(crow0 + i * 16 + r2);
#pragma unroll
      for (int j = 0; j < 4; ++j) {
        const int col = ccol0 + j * 16;
        float v = acc[i][j][r2];
        if (EPI == 2) v = fmaxf(v + bias[col], 0.0f);
        Cz[row * (size_t)ldc + col] = (f16)v;
      }
    }
  }
}

// bijective XCD-chunked swizzle (T1): block with HW id `id` (XCD = id%8)
// computes tile nid from its XCD's contiguous chunk.
__device__ __forceinline__ int xcd_swizzle(int id, int nwg) {
  const int q = nwg >> 3, r = nwg & 7;
  const int xcd = id & 7, lin = id >> 3;
  return (xcd < r ? xcd * (q + 1) : r * (q + 1) + (xcd - r) * q) + lin;
}

// ---------------------------------------------------------------------------
// generic NT wrapper: C = A*B^T, split-K via gridDim.z, f16 slabs at
// Ch + z*M*ldc.
// ---------------------------------------------------------------------------
template <int EPI>
__global__ __launch_bounds__(512, 2) void gemm_nt256(
    const f16* __restrict__ A, const f16* __restrict__ B,
    f16* __restrict__ Ch, const float* __restrict__ bias,
    int M, int Nc, int K, int lda, int ldb, int ldc) {
  __shared__ f16 sm[4][256 * 64];
  const int gx = gridDim.x, gy = gridDim.y;
  const int nwg = gx * gy * gridDim.z;
  const int id = blockIdx.x + gx * (blockIdx.y + gy * blockIdx.z);
  const int nid = xcd_swizzle(id, nwg);
  const int bx = nid % gx;
  const int by = (nid / gx) % gy;
  const int bz = nid / (gx * gy);
  const int kper = K / gridDim.z;
  gemm256_core<EPI>(A, B, Ch + (size_t)bz * M * ldc, bias, lda, ldb, ldc,
                    kper, bz * kper, by << 8, bx << 8, &sm[0][0]);
}

// ---------------------------------------------------------------------------
// weight precompose on the 8-phase core: grid (4,4,16).
// z<8: parQK slab zz = Wkb@Wqb^T (K=4096 split 8); z>=8: parVO = WoT@Wvb^T.
// ---------------------------------------------------------------------------
__global__ __launch_bounds__(512, 2) void gemm_pre256(
    const f16* __restrict__ Wkb, const f16* __restrict__ Wqb,
    const f16* __restrict__ WoT, const f16* __restrict__ Wvb,
    f16* __restrict__ parQK, f16* __restrict__ parVO, int D, int H) {
  __shared__ f16 sm[4][256 * 64];
  const int id = blockIdx.x + 4 * (blockIdx.y + 4 * blockIdx.z);
  const int nid = xcd_swizzle(id, 256);
  const int bx = nid & 3, by = (nid >> 2) & 3, z = nid >> 4;
  const int zz = z & 7;
  const f16* A = (z < 8) ? Wkb : WoT;
  const f16* B = (z < 8) ? Wqb : Wvb;
  f16* slab = ((z < 8) ? parQK : parVO) + (size_t)zz * D * D;
  gemm256_core<1>(A, B, slab, nullptr, H, H, D, H / 8, zz * (H / 8),
                  by << 8, bx << 8, &sm[0][0]);
}

// ---------------------------------------------------------------------------
// merged th/xvoT on the 8-phase core: grid (4,32).
// y<16: th = xb@WqkT^T [N,D] (bm=y,bn=x); y>=16: xvoT = WvoT@xb^T [D,N].
// ---------------------------------------------------------------------------
__global__ __launch_bounds__(512, 2) void gemm_dual256(
    const f16* __restrict__ xb, const f16* __restrict__ WqkT,
    const f16* __restrict__ WvoT, f16* __restrict__ th,
    f16* __restrict__ xvoT, int N, int D) {
  __shared__ f16 sm[4][256 * 64];
  const int id = blockIdx.x + 4 * blockIdx.y;
  const int nid = xcd_swizzle(id, 128);
  const int bx = nid & 3, y = nid >> 2;
  if (y < 16)
    gemm256_core<1>(xb, WqkT, th, nullptr, D, D, D, D, 0,
                    y << 8, bx << 8, &sm[0][0]);
  else
    gemm256_core<1>(WvoT, xb, xvoT, nullptr, D, D, N, D, 0,
                    bx << 8, (y - 16) << 8, &sm[0][0]);
}

// ---------------------------------------------------------------------------
// fused input prep, grid (2048, 7), block 256 -- fully vectorized.
// z 0..2: transposes (first 1024 blocks): W1->W1T, Wo->WoT, W2->W2T via
//   64x64 LDS tile, XOR-swizzled layout lt[c*64 + (r ^ ((c&7)<<3))] so both
//   the LDS read and the global store of the output are 16B vectors.
// z 3..6: converts x/Wq/Wk/Wv -> f16, 2x float4 in, 1x half8 out per lane.
// ---------------------------------------------------------------------------
__global__ void prep_inputs(const float* x, const float* Wq, const float* Wk,
                            const float* Wv, const float* W1, const float* Wo,
                            const float* W2, f16* xb, f16* Wqb, f16* Wkb,
                            f16* Wvb, f16* W1T, f16* WoT, f16* W2T) {
  const int z = blockIdx.y;
  const int b = blockIdx.x;
  const int t = threadIdx.x;
  if (z >= 3) {  // converts: 4M elems each, 2048 blocks x 256 thr x 8 elems
    const float* in = (z == 3) ? x : (z == 4) ? Wq : (z == 5) ? Wk : Wv;
    f16* out = (z == 3) ? xb : (z == 4) ? Wqb : (z == 5) ? Wkb : Wvb;
    const size_t i = ((size_t)b * 256 + t) * 8;
    const float4 a = *(const float4*)(in + i);
    const float4 c = *(const float4*)(in + i + 4);
    half8 v = {(f16)a.x, (f16)a.y, (f16)a.z, (f16)a.w,
               (f16)c.x, (f16)c.y, (f16)c.z, (f16)c.w};
    *(half8*)(out + i) = v;
    return;
  }
  if (b >= 1024) return;  // transposes: 1024 64x64 tiles each
  int R, C, tx, ty;
  const float* in;
  f16* out;
  if (z == 0) {
    R = 1024; C = 4096; in = W1; out = W1T;
    tx = b & 63; ty = b >> 6;
  } else {
    R = 4096; C = 1024; in = (z == 1) ? Wo : W2;
    out = (z == 1) ? WoT : W2T;
    tx = b & 15; ty = b >> 4;
  }
  const int r0 = ty << 6, c0 = tx << 6;
  __shared__ f16 lt[64 * 64];
  const int lr = t >> 4, lc = t & 15;
#pragma unroll
  for (int rr = 0; rr < 4; ++rr) {
    const int r = lr + rr * 16;
    const float4 f = *(const float4*)(in + (size_t)(r0 + r) * C + c0 + lc * 4);
    const float fv[4] = {f.x, f.y, f.z, f.w};
#pragma unroll
    for (int j = 0; j < 4; ++j) {
      const int c = lc * 4 + j;
      lt[c * 64 + (r ^ ((c & 7) << 3))] = (f16)fv[j];
    }
  }
  __syncthreads();
  const int oc = t >> 3, orr = (t & 7) << 3;
#pragma unroll
  for (int cc = 0; cc < 2; ++cc) {
    const int c = oc + cc * 32;
    const half8 v = *(const half8*)(lt + c * 64 + (orr ^ ((c & 7) << 3)));
    *(half8*)(out + (size_t)(c0 + c) * R + r0 + orr) = v;
  }
}

// ---------------------------------------------------------------------------
// merged slab reduce: first n/1024 blocks sum 8 f16 slabs parQK -> WqkT,
// remaining blocks do parVO -> WvoT. n = D*D.
// ---------------------------------------------------------------------------
__global__ void reduce_dual(const f16* __restrict__ parQK,
                            const f16* __restrict__ parVO,
                            f16* __restrict__ WqkT, f16* __restrict__ WvoT,
                            int n) {
  const int half = gridDim.x >> 1;
  const bool second = blockIdx.x >= half;
  const f16* par = second ? parVO : parQK;
  f16* out = second ? WvoT : WqkT;
  const int b = second ? blockIdx.x - half : blockIdx.x;
  const int i = (b * 256 + threadIdx.x) * 4;
  float s0 = 0, s1 = 0, s2 = 0, s3 = 0;
#pragma unroll
  for (int z = 0; z < 8; ++z) {
    const half4 p = *(const half4*)(par + (size_t)z * n + i);
    s0 += (float)p[0]; s1 += (float)p[1]; s2 += (float)p[2]; s3 += (float)p[3];
  }
  half4 o = {(f16)s0, (f16)s1, (f16)s2, (f16)s3};
  *(half4*)(out + i) = o;
}

// ---------------------------------------------------------------------------
// row softmax: f16 S[row,:N] -> f16 P. One 256-thread block per row, N=4096.
// ---------------------------------------------------------------------------
__global__ void softmax_rows(const f16* __restrict__ S, f16* __restrict__ P,
                             int N) {
  const int row = blockIdx.x;
  const int t = threadIdx.x;
  const int lane = t & 63, wave = t >> 6;
  const f16* s = S + (size_t)row * N;
  const half8 a = *(const half8*)(s + t * 8);
  const half8 b = *(const half8*)(s + 2048 + t * 8);
  float v[16];
#pragma unroll
  for (int i = 0; i < 8; ++i) {
    v[i] = (float)a[i];
    v[8 + i] = (float)b[i];
  }
  float mx = -1e30f;
#pragma unroll
  for (int i = 0; i < 16; ++i) mx = fmaxf(mx, v[i]);
#pragma unroll
  for (int off = 32; off > 0; off >>= 1) mx = fmaxf(mx, __shfl_xor(mx, off));
  __shared__ float red[8];
  if (lane == 0) red[wave] = mx;
  __syncthreads();
  mx = fmaxf(fmaxf(red[0], red[1]), fmaxf(red[2], red[3]));
  float sum = 0.0f;
#pragma unroll
  for (int i = 0; i < 16; ++i) {
    v[i] = __expf(v[i] - mx);
    sum += v[i];
  }
#pragma unroll
  for (int off = 32; off > 0; off >>= 1) sum += __shfl_xor(sum, off);
  if (lane == 0) red[4 + wave] = sum;
  __syncthreads();
  const float inv = 1.0f / (red[4] + red[5] + red[6] + red[7]);
  f16* p = P + (size_t)row * N;
  half8 oa, ob;
#pragma unroll
  for (int i = 0; i < 8; ++i) {
    oa[i] = (f16)(v[i] * inv);
    ob[i] = (f16)(v[8 + i] * inv);
  }
  *(half8*)(p + t * 8) = oa;
  *(half8*)(p + 2048 + t * 8) = ob;
}

// ---------------------------------------------------------------------------
// fused residual + f16 split-K slab reduce + (optional bias) + LayerNorm.
// One block per row, D=1024. b = base of nchunks f16 slabs, stride cs elems.
// ---------------------------------------------------------------------------
__global__ void add_ln(const float* __restrict__ a, const f16* __restrict__ b,
                       int nchunks, size_t cs, const float* __restrict__ bias,
                       const float* __restrict__ g, const float* __restrict__ be,
                       float* __restrict__ outf, f16* __restrict__ outh, int D) {
  const int row = blockIdx.x;
  const int t = threadIdx.x;
  const int lane = t & 63, wave = t >> 6;
  const float4 av = *(const float4*)(a + (size_t)row * D + t * 4);
  float s[4] = {av.x, av.y, av.z, av.w};
  for (int c = 0; c < nchunks; ++c) {
    const half4 bv = *(const half4*)(b + c * cs + (size_t)row * D + t * 4);
    s[0] += (float)bv[0]; s[1] += (float)bv[1];
    s[2] += (float)bv[2]; s[3] += (float)bv[3];
  }
  if (bias != nullptr) {
    const float4 bb = *(const float4*)(bias + t * 4);
    s[0] += bb.x; s[1] += bb.y; s[2] += bb.z; s[3] += bb.w;
  }
  float sum = s[0] + s[1] + s[2] + s[3];
  float sq = s[0] * s[0] + s[1] * s[1] + s[2] * s[2] + s[3] * s[3];
#pragma unroll
  for (int off = 32; off > 0; off >>= 1) {
    sum += __shfl_xor(sum, off);
    sq += __shfl_xor(sq, off);
  }
  __shared__ float red[8];
  if (lane == 0) {
    red[wave] = sum;
    red[4 + wave] = sq;
  }
  __syncthreads();
  sum = red[0] + red[1] + red[2] + red[3];
  sq = red[4] + red[5] + red[6] + red[7];
  const float mu = sum / (float)D;
  const float rv = rsqrtf(sq / (float)D - mu * mu + LN_EPS);
  const float4 gv = *(const float4*)(g + t * 4);
  const float4 bev = *(const float4*)(be + t * 4);
  float y0 = (s[0] - mu) * rv * gv.x + bev.x;
  float y1 = (s[1] - mu) * rv * gv.y + bev.y;
  float y2 = (s[2] - mu) * rv * gv.z + bev.z;
  float y3 = (s[3] - mu) * rv * gv.w + bev.w;
  if (outf != nullptr) {
    float4 o = {y0, y1, y2, y3};
    *(float4*)(outf + (size_t)row * D + t * 4) = o;
  }
  if (outh != nullptr) {
    f16* ob = outh + (size_t)row * D + t * 4;
    ob[0] = (f16)y0;
    ob[1] = (f16)y1;
    ob[2] = (f16)y2;
    ob[3] = (f16)y3;
  }
}

// ---------------------------------------------------------------------------
// launch
// ---------------------------------------------------------------------------
extern "C" void kernel_launch(void* const* d_in, const int* in_sizes, int n_in,
                              void* d_out, int out_size, void* d_ws,
                              size_t ws_size, hipStream_t stream) {
  constexpr int N = 4096, D = 1024, H = 4096;
  const float* x = (const float*)d_in[0];
  const float* Wq = (const float*)d_in[1];
  const float* Wk = (const float*)d_in[2];
  const float* Wv = (const float*)d_in[3];
  const float* Wo = (const float*)d_in[4];
  const float* W1 = (const float*)d_in[5];
  const float* b1 = (const float*)d_in[6];
  const float* W2 = (const float*)d_in[7];
  const float* b2 = (const float*)d_in[8];
  const float* g1 = (const float*)d_in[9];
  const float* be1 = (const float*)d_in[10];
  const float* g2 = (const float*)d_in[11];
  const float* be2 = (const float*)d_in[12];
  float* out = (float*)d_out;

  const size_t MB = 1024ull * 1024ull;
  char* w = (char*)d_ws;
  // workspace layout (228 MB used; hazard-checked reuse; offsets in MB):
  f16* xb   = (f16*)(w + 0 * MB);     // 8   [N,D]
  f16* Wqb  = (f16*)(w + 8 * MB);     // 8   [D,H]
  f16* Wkb  = (f16*)(w + 16 * MB);    // 8   [D,H]
  f16* Wvb  = (f16*)(w + 24 * MB);    // 8   [D,H]
  f16* WoT  = (f16*)(w + 32 * MB);    // 8   [D,H]
  f16* W1T  = (f16*)(w + 40 * MB);    // 8   [H,D]
  f16* W2T  = (f16*)(w + 48 * MB);    // 8   [D,H]
  f16* WqkT = (f16*)(w + 56 * MB);    // 2   [D,D] = (Wq@Wk^T)^T
  f16* WvoT = (f16*)(w + 58 * MB);    // 2   [D,D] = (Wv@Wo)^T
  f16* th   = (f16*)(w + 60 * MB);    // 8   [N,D]; dead after S
  f16* xvoT = (f16*)(w + 68 * MB);    // 8   [D,N]
  f16* F1   = (f16*)(w + 76 * MB);    // 32  [N,H]
  f16* Sh   = (f16*)(w + 108 * MB);   // 32  [N,N] f16; dead after softmax
  f16* parA = (f16*)(w + 108 * MB);   // 4x8MB f16 slabs (over dead Sh)
  f16* Pb   = (f16*)(w + 140 * MB);   // 32  [N,N]; dead after attn
  float* hf = (float*)(w + 172 * MB); // 16  [N,D]
  f16* hb   = (f16*)(w + 188 * MB);   // 8   [N,D]
  f16* parQK = (f16*)(w + 196 * MB);  // 16 = 8x2MB f16 slabs; dead after reduce
  f16* parVO = (f16*)(w + 212 * MB);  // 16 = 8x2MB f16 slabs; dead after reduce

  // ---- input prep: 4 converts + 3 transposes, ONE dispatch, vectorized ----
  prep_inputs<<<dim3(2048, 7), 256, 0, stream>>>(
      x, Wq, Wk, Wv, W1, Wo, W2, xb, Wqb, Wkb, Wvb, W1T, WoT, W2T);

  // ---- weight precomposition (both [D,D] composites, one dispatch) ----
  gemm_pre256<<<dim3(4, 4, 16), 512, 0, stream>>>(
      Wkb, Wqb, WoT, Wvb, parQK, parVO, D, H);
  reduce_dual<<<2 * (D * D) / 1024, 256, 0, stream>>>(parQK, parVO, WqkT,
                                                      WvoT, D * D);

  // ---- attention ----
  // th = xb@WqkT^T [N,D] and xvoT = WvoT@xb^T [D,N], one dispatch
  gemm_dual256<<<dim3(4, 32), 512, 0, stream>>>(xb, WqkT, WvoT, th, xvoT,
                                                N, D);
  // S = th @ xb^T  [N,N] f16 logits (K=1024), 256^2 8-phase kernel
  gemm_nt256<1><<<dim3(N / 256, N / 256, 1), 512, 0, stream>>>(
      th, xb, Sh, nullptr, N, N, D, D, D, N);
  softmax_rows<<<N, 256, 0, stream>>>(Sh, Pb, N);
  // attn partials = Pb @ xvoT^T  [N,D], split-K=4, f16 slabs (over dead Sh)
  gemm_nt256<1><<<dim3(D / 256, N / 256, 4), 512, 0, stream>>>(
      Pb, xvoT, parA, nullptr, N, D, N, N, N, D);
  // h = LN(x + sum(attn partials))
  add_ln<<<N, 256, 0, stream>>>(x, parA, 4, (size_t)N * D, nullptr, g1, be1,
                                hf, hb, D);

  // ---- feed-forward ----
  // F1 = relu(hb @ W1T^T + b1)  [N,H] f16
  gemm_nt256<2><<<dim3(H / 256, N / 256, 1), 512, 0, stream>>>(
      hb, W1T, F1, b1, N, H, D, D, D, H);
  // F2 partials = F1 @ W2T^T  [N,D], split-K=4, f16 slabs
  gemm_nt256<1><<<dim3(D / 256, N / 256, 4), 512, 0, stream>>>(
      F1, W2T, parA, nullptr, N, D, H, H, H, D);
  // out = LN(hf + sum(F2 partials) + b2)
  add_ln<<<N, 256, 0, stream>>>(hf, parA, 4, (size_t)N * D, b2, g2, be2,
                                out, nullptr, D);
}

// Round 3
// 404.352 us; speedup vs baseline: 1.2666x; 1.0045x over previous
//
#include <hip/hip_runtime.h>
#include <hip/hip_bf16.h>

using f16 = _Float16;
typedef __attribute__((ext_vector_type(8))) f16 half8;
typedef __attribute__((ext_vector_type(4))) f16 half4;
typedef __attribute__((ext_vector_type(4))) float floatx4;

#define LN_EPS 1e-5f

// ---------------------------------------------------------------------------
// async global->LDS, 16B per lane. LDS dest is wave-uniform base + lane*16.
// ---------------------------------------------------------------------------
__device__ __forceinline__ void gload_lds16(const f16* g, f16* l) {
  __builtin_amdgcn_global_load_lds(
      (const __attribute__((address_space(1))) void*)g,
      (__attribute__((address_space(3))) void*)l, 16, 0, 0);
}

#define CFENCE asm volatile("" ::: "memory")
#define WAIT_VM(N) asm volatile("s_waitcnt vmcnt(" #N ")" ::: "memory")
#define BARRIER()                    \
  do {                               \
    CFENCE;                          \
    __builtin_amdgcn_s_barrier();    \
    CFENCE;                          \
  } while (0)

// ---------------------------------------------------------------------------
// 256x256-tile 8-phase pipelined GEMM core (T1+T2+T3+T4+T5), 512 thr
// (8 waves, 2Mx4N), BK=64, per-wave output 128x64 (acc[8][4] f32x4),
// 128 KiB LDS (2 K-tile buffers x (A 256x64 + B 256x64) f16).
// Schedule identical to the round-1 harness-verified kernel.
// ---------------------------------------------------------------------------
template <int EPI>
__device__ __forceinline__ void gemm256_core(
    const f16* __restrict__ A, const f16* __restrict__ B,
    f16* __restrict__ Cz, const float* __restrict__ bias,
    int lda, int ldb, int ldc, int kper, int kbeg, int bm, int bn,
    f16* smp) {
  const int t = threadIdx.x;
  const int wave = t >> 6, lane = t & 63;
  const int wm = (wave >> 2) << 7;  // wave M offset: 0/128
  const int wn = (wave & 3) << 6;   // wave N offset: 0/64/128/192
  const int lrow = lane & 15, lkc = lane >> 4;

  // staging: seg = wave*2+l covers 8 rows of a 128-row half-tile
  const int srow = lane >> 3;
  const int schunk = ((lane & 7) ^ srow) << 3;  // swizzled source chunk (elems)
  const f16* Ag = A + (size_t)(bm + wave * 16 + srow) * lda + kbeg + schunk;
  const f16* Bg = B + (size_t)(bn + wave * 16 + srow) * ldb + kbeg + schunk;

  // swizzled fragment k-offsets (elems within 64-elem row), kk = 0 / 1
  const int co0 = ((lkc ^ (lrow & 7)) << 3);
  const int co1 = (((4 + lkc) ^ (lrow & 7)) << 3);

  floatx4 acc[8][4] = {};
  half8 af[4][2];       // one qm-half of A frags, both kk
  half8 bf[2][2][2];    // [qn][fn][kk] -- both qn halves live

  auto STAGE = [&](int b, int tt, int h) {  // h: 0=A-lo 1=A-hi 2=B-lo 3=B-hi
    if (h < 2) {
      const f16* src = Ag + (size_t)(h * 128) * lda + tt * 64;
      f16* d = smp + (b * 2) * 16384 + h * 8192 + wave * 1024;
      gload_lds16(src, d);
      gload_lds16(src + (size_t)8 * lda, d + 512);
    } else {
      const f16* src = Bg + (size_t)((h - 2) * 128) * ldb + tt * 64;
      f16* d = smp + (b * 2 + 1) * 16384 + (h - 2) * 8192 + wave * 1024;
      gload_lds16(src, d);
      gload_lds16(src + (size_t)8 * ldb, d + 512);
    }
  };
  auto LDA = [&](int b, int qm) {
    const f16* base = smp + (b * 2) * 16384 + (wm + qm * 64 + lrow) * 64;
#pragma unroll
    for (int fm = 0; fm < 4; ++fm) {
      af[fm][0] = *(const half8*)(base + fm * (16 * 64) + co0);
      af[fm][1] = *(const half8*)(base + fm * (16 * 64) + co1);
    }
  };
  auto LDB = [&](int b, int qn) {
    const f16* base = smp + (b * 2 + 1) * 16384 + (wn + qn * 32 + lrow) * 64;
#pragma unroll
    for (int fn = 0; fn < 2; ++fn) {
      bf[qn][fn][0] = *(const half8*)(base + fn * (16 * 64) + co0);
      bf[qn][fn][1] = *(const half8*)(base + fn * (16 * 64) + co1);
    }
  };
  auto MFMAQ = [&](int qm, int qn) {
    __builtin_amdgcn_s_setprio(1);
#pragma unroll
    for (int kk = 0; kk < 2; ++kk)
#pragma unroll
      for (int fm = 0; fm < 4; ++fm)
#pragma unroll
        for (int fn = 0; fn < 2; ++fn)
          acc[qm * 4 + fm][qn * 2 + fn] =
              __builtin_amdgcn_mfma_f32_16x16x32_f16(
                  af[fm][kk], bf[qn][fn][kk], acc[qm * 4 + fm][qn * 2 + fn],
                  0, 0, 0);
    __builtin_amdgcn_s_setprio(0);
  };

  const int NT = kper >> 6;  // K-tiles (even for all call sites)
  const int NI = NT >> 1;

  // prologue: tile0 -> buf0 (4 halves), tile1 half0 -> buf1; wait tile0
  STAGE(0, 0, 0); STAGE(0, 0, 1); STAGE(0, 0, 2); STAGE(0, 0, 3);
  STAGE(1, 1, 0);
  WAIT_VM(2);
  BARRIER();

  for (int i = 0; i < NI; ++i) {
    const bool last = (i == NI - 1);
    const int tb = 2 * i;
    // P0 -- t0 Q(0,0)
    LDA(0, 0); LDB(0, 0); STAGE(1, tb + 1, 1);
    BARRIER(); MFMAQ(0, 0); BARRIER();
    // P1 -- t0 Q(0,1)
    LDB(0, 1); STAGE(1, tb + 1, 2);
    BARRIER(); MFMAQ(0, 1); BARRIER();
    // P2 -- t0 Q(1,0)
    LDA(0, 1); STAGE(1, tb + 1, 3);
    BARRIER(); MFMAQ(1, 0); BARRIER();
    // P3 -- t0 Q(1,1); guarantee tile t1 landed before P4 reads buf1
    if (!last) {
      STAGE(0, tb + 2, 0);
      WAIT_VM(2);
    } else {
      WAIT_VM(0);
    }
    BARRIER(); MFMAQ(1, 1); BARRIER();
    // P4 -- t1 Q(0,0)
    LDA(1, 0); LDB(1, 0);
    if (!last) STAGE(0, tb + 2, 1);
    BARRIER(); MFMAQ(0, 0); BARRIER();
    // P5 -- t1 Q(0,1)
    LDB(1, 1);
    if (!last) STAGE(0, tb + 2, 2);
    BARRIER(); MFMAQ(0, 1); BARRIER();
    // P6 -- t1 Q(1,0)
    LDA(1, 1);
    if (!last) STAGE(0, tb + 2, 3);
    BARRIER(); MFMAQ(1, 0); BARRIER();
    // P7 -- t1 Q(1,1); guarantee tile t0+2 landed before next P0 reads buf0
    if (!last) {
      STAGE(1, tb + 3, 0);
      WAIT_VM(2);
    }
    BARRIER(); MFMAQ(1, 1); BARRIER();
  }

  // epilogue: C/D col = lane&15, row = (lane>>4)*4 + reg
  const int crow0 = bm + wm + lkc * 4;
  const int ccol0 = bn + wn + lrow;
#pragma unroll
  for (int i = 0; i < 8; ++i) {
#pragma unroll
    for (int r2 = 0; r2 < 4; ++r2) {
      const size_t row = (size_t)(crow0 + i * 16 + r2);
#pragma unroll
      for (int j = 0; j < 4; ++j) {
        const int col = ccol0 + j * 16;
        float v = acc[i][j][r2];
        if (EPI == 2) v = fmaxf(v + bias[col], 0.0f);
        Cz[row * (size_t)ldc + col] = (f16)v;
      }
    }
  }
}

// bijective XCD-chunked swizzle (T1): block with HW id `id` (XCD = id%8)
// computes tile nid from its XCD's contiguous chunk.
__device__ __forceinline__ int xcd_swizzle(int id, int nwg) {
  const int q = nwg >> 3, r = nwg & 7;
  const int xcd = id & 7, lin = id >> 3;
  return (xcd < r ? xcd * (q + 1) : r * (q + 1) + (xcd - r) * q) + lin;
}

// ---------------------------------------------------------------------------
// generic NT wrapper: C = A*B^T, split-K via gridDim.z, f16 slabs at
// Ch + z*M*ldc.
// ---------------------------------------------------------------------------
template <int EPI>
__global__ __launch_bounds__(512, 2) void gemm_nt256(
    const f16* __restrict__ A, const f16* __restrict__ B,
    f16* __restrict__ Ch, const float* __restrict__ bias,
    int M, int Nc, int K, int lda, int ldb, int ldc) {
  __shared__ f16 sm[4][256 * 64];
  const int gx = gridDim.x, gy = gridDim.y;
  const int nwg = gx * gy * gridDim.z;
  const int id = blockIdx.x + gx * (blockIdx.y + gy * blockIdx.z);
  const int nid = xcd_swizzle(id, nwg);
  const int bx = nid % gx;
  const int by = (nid / gx) % gy;
  const int bz = nid / (gx * gy);
  const int kper = K / gridDim.z;
  gemm256_core<EPI>(A, B, Ch + (size_t)bz * M * ldc, bias, lda, ldb, ldc,
                    kper, bz * kper, by << 8, bx << 8, &sm[0][0]);
}

// ---------------------------------------------------------------------------
// weight precompose on the 8-phase core: grid (4,4,16).
// z<8: parQK slab zz = Wkb@Wqb^T (K=4096 split 8); z>=8: parVO = WoT@Wvb^T.
// ---------------------------------------------------------------------------
__global__ __launch_bounds__(512, 2) void gemm_pre256(
    const f16* __restrict__ Wkb, const f16* __restrict__ Wqb,
    const f16* __restrict__ WoT, const f16* __restrict__ Wvb,
    f16* __restrict__ parQK, f16* __restrict__ parVO, int D, int H) {
  __shared__ f16 sm[4][256 * 64];
  const int id = blockIdx.x + 4 * (blockIdx.y + 4 * blockIdx.z);
  const int nid = xcd_swizzle(id, 256);
  const int bx = nid & 3, by = (nid >> 2) & 3, z = nid >> 4;
  const int zz = z & 7;
  const f16* A = (z < 8) ? Wkb : WoT;
  const f16* B = (z < 8) ? Wqb : Wvb;
  f16* slab = ((z < 8) ? parQK : parVO) + (size_t)zz * D * D;
  gemm256_core<1>(A, B, slab, nullptr, H, H, D, H / 8, zz * (H / 8),
                  by << 8, bx << 8, &sm[0][0]);
}

// ---------------------------------------------------------------------------
// merged th/xvoT on the 8-phase core: grid (4,32).
// y<16: th = xb@WqkT^T [N,D] (bm=y,bn=x); y>=16: xvoT = WvoT@xb^T [D,N].
// ---------------------------------------------------------------------------
__global__ __launch_bounds__(512, 2) void gemm_dual256(
    const f16* __restrict__ xb, const f16* __restrict__ WqkT,
    const f16* __restrict__ WvoT, f16* __restrict__ th,
    f16* __restrict__ xvoT, int N, int D) {
  __shared__ f16 sm[4][256 * 64];
  const int id = blockIdx.x + 4 * blockIdx.y;
  const int nid = xcd_swizzle(id, 128);
  const int bx = nid & 3, y = nid >> 2;
  if (y < 16)
    gemm256_core<1>(xb, WqkT, th, nullptr, D, D, D, D, 0,
                    y << 8, bx << 8, &sm[0][0]);
  else
    gemm256_core<1>(WvoT, xb, xvoT, nullptr, D, D, N, D, 0,
                    bx << 8, (y - 16) << 8, &sm[0][0]);
}

// ---------------------------------------------------------------------------
// fused input prep, grid (1024, 7), block 256 -- fully vectorized.
// z 0..2: transposes: W1->W1T, Wo->WoT, W2->W2T. Per 64x64 f32 tile:
//   coalesced float4 reads; in-register 4x4 transpose via __shfl_xor
//   (masks 32 then 16) among the 4 lanes (bits 4/5) holding 4 consecutive
//   rows of the same 16B column chunk; then ONE ds_write_b64 per lane per
//   iteration into column-major LDS with bank-exact swizzle
//   r' = r ^ ((c&15)<<2) (b64 granularity on both sides = intrinsic-minimum
//   bank utilization, no conflicts). Output: 2x ds_read_b64 -> one 16B
//   coalesced global store.
// z 3..6: converts x/Wq/Wk/Wv -> f16, 4x float4 in, 2x half8 out per lane.
// ---------------------------------------------------------------------------
__global__ void prep_inputs(const float* x, const float* Wq, const float* Wk,
                            const float* Wv, const float* W1, const float* Wo,
                            const float* W2, f16* xb, f16* Wqb, f16* Wkb,
                            f16* Wvb, f16* W1T, f16* WoT, f16* W2T) {
  const int z = blockIdx.y;
  const int b = blockIdx.x;
  const int t = threadIdx.x;
  if (z >= 3) {  // converts: 4M elems each, 1024 blocks x 256 thr x 16 elems
    const float* in = (z == 3) ? x : (z == 4) ? Wq : (z == 5) ? Wk : Wv;
    f16* out = (z == 3) ? xb : (z == 4) ? Wqb : (z == 5) ? Wkb : Wvb;
    const size_t i = ((size_t)b * 256 + t) * 16;
    const float4 a0 = *(const float4*)(in + i);
    const float4 a1 = *(const float4*)(in + i + 4);
    const float4 a2 = *(const float4*)(in + i + 8);
    const float4 a3 = *(const float4*)(in + i + 12);
    half8 v0 = {(f16)a0.x, (f16)a0.y, (f16)a0.z, (f16)a0.w,
                (f16)a1.x, (f16)a1.y, (f16)a1.z, (f16)a1.w};
    half8 v1 = {(f16)a2.x, (f16)a2.y, (f16)a2.z, (f16)a2.w,
                (f16)a3.x, (f16)a3.y, (f16)a3.z, (f16)a3.w};
    *(half8*)(out + i) = v0;
    *(half8*)(out + i + 8) = v1;
    return;
  }
  int R, C, tx, ty;
  const float* in;
  f16* out;
  if (z == 0) {
    R = 1024; C = 4096; in = W1; out = W1T;
    tx = b & 63; ty = b >> 6;
  } else {
    R = 4096; C = 1024; in = (z == 1) ? Wo : W2;
    out = (z == 1) ? WoT : W2T;
    tx = b & 15; ty = b >> 4;
  }
  const int r0 = ty << 6, c0 = tx << 6;
  __shared__ f16 lt[64 * 64];
  const int lr = t >> 4;          // 0..15: row-chunk id
  const int lc = t & 15;          // col-chunk id (16B = 4 floats)
  const int q3 = lr & 3;          // lane bits 4..5: row within 4x4 block
  const int rb = lr & ~3;         // 4-row block base (wave-uniform)
  const int myc = lc * 4 + q3;    // column owned after transpose
#pragma unroll
  for (int rr = 0; rr < 4; ++rr) {
    const int r = lr + rr * 16;
    const float4 f = *(const float4*)(in + (size_t)(r0 + r) * C + c0 + lc * 4);
    float v0 = f.x, v1 = f.y, v2 = f.z, v3 = f.w;
    // 4x4 transpose among lanes {t ^ 16, t ^ 32}: block swap (mask 32)...
    {
      const bool hi = (q3 & 2) != 0;
      float sA = hi ? v0 : v2;
      float sB = hi ? v1 : v3;
      sA = __shfl_xor(sA, 32);
      sB = __shfl_xor(sB, 32);
      if (hi) { v0 = sA; v1 = sB; } else { v2 = sA; v3 = sB; }
    }
    // ...then in-block 2x2 transpose (mask 16)
    {
      const bool od = (q3 & 1) != 0;
      float sC = od ? v0 : v1;
      float sD = od ? v2 : v3;
      sC = __shfl_xor(sC, 16);
      sD = __shfl_xor(sD, 16);
      if (od) { v0 = sC; v2 = sD; } else { v1 = sC; v3 = sD; }
    }
    // lane now holds rows (rb + rr*16 + 0..3) of column myc
    half4 hv = {(f16)v0, (f16)v1, (f16)v2, (f16)v3};
    const int rbase = rb + rr * 16;
    *(half4*)(lt + myc * 64 + (rbase ^ ((myc & 15) << 2))) = hv;
  }
  __syncthreads();
  const int oc = t >> 3, orr = (t & 7) << 3;
#pragma unroll
  for (int cc = 0; cc < 2; ++cc) {
    const int c = oc + cc * 32;
    const int swz = (c & 15) << 2;
    const half4 ha = *(const half4*)(lt + c * 64 + (orr ^ swz));
    const half4 hb4 = *(const half4*)(lt + c * 64 + ((orr + 4) ^ swz));
    half8 v = {ha[0], ha[1], ha[2], ha[3], hb4[0], hb4[1], hb4[2], hb4[3]};
    *(half8*)(out + (size_t)(c0 + c) * R + r0 + orr) = v;
  }
}

// ---------------------------------------------------------------------------
// merged slab reduce: first n/1024 blocks sum 8 f16 slabs parQK -> WqkT,
// remaining blocks do parVO -> WvoT. n = D*D.
// ---------------------------------------------------------------------------
__global__ void reduce_dual(const f16* __restrict__ parQK,
                            const f16* __restrict__ parVO,
                            f16* __restrict__ WqkT, f16* __restrict__ WvoT,
                            int n) {
  const int half = gridDim.x >> 1;
  const bool second = blockIdx.x >= half;
  const f16* par = second ? parVO : parQK;
  f16* out = second ? WvoT : WqkT;
  const int b = second ? blockIdx.x - half : blockIdx.x;
  const int i = (b * 256 + threadIdx.x) * 4;
  float s0 = 0, s1 = 0, s2 = 0, s3 = 0;
#pragma unroll
  for (int z = 0; z < 8; ++z) {
    const half4 p = *(const half4*)(par + (size_t)z * n + i);
    s0 += (float)p[0]; s1 += (float)p[1]; s2 += (float)p[2]; s3 += (float)p[3];
  }
  half4 o = {(f16)s0, (f16)s1, (f16)s2, (f16)s3};
  *(half4*)(out + i) = o;
}

// ---------------------------------------------------------------------------
// row softmax: f16 S[row,:N] -> f16 P. One 256-thread block per row, N=4096.
// ---------------------------------------------------------------------------
__global__ void softmax_rows(const f16* __restrict__ S, f16* __restrict__ P,
                             int N) {
  const int row = blockIdx.x;
  const int t = threadIdx.x;
  const int lane = t & 63, wave = t >> 6;
  const f16* s = S + (size_t)row * N;
  const half8 a = *(const half8*)(s + t * 8);
  const half8 b = *(const half8*)(s + 2048 + t * 8);
  float v[16];
#pragma unroll
  for (int i = 0; i < 8; ++i) {
    v[i] = (float)a[i];
    v[8 + i] = (float)b[i];
  }
  float mx = -1e30f;
#pragma unroll
  for (int i = 0; i < 16; ++i) mx = fmaxf(mx, v[i]);
#pragma unroll
  for (int off = 32; off > 0; off >>= 1) mx = fmaxf(mx, __shfl_xor(mx, off));
  __shared__ float red[8];
  if (lane == 0) red[wave] = mx;
  __syncthreads();
  mx = fmaxf(fmaxf(red[0], red[1]), fmaxf(red[2], red[3]));
  float sum = 0.0f;
#pragma unroll
  for (int i = 0; i < 16; ++i) {
    v[i] = __expf(v[i] - mx);
    sum += v[i];
  }
#pragma unroll
  for (int off = 32; off > 0; off >>= 1) sum += __shfl_xor(sum, off);
  if (lane == 0) red[4 + wave] = sum;
  __syncthreads();
  const float inv = 1.0f / (red[4] + red[5] + red[6] + red[7]);
  f16* p = P + (size_t)row * N;
  half8 oa, ob;
#pragma unroll
  for (int i = 0; i < 8; ++i) {
    oa[i] = (f16)(v[i] * inv);
    ob[i] = (f16)(v[8 + i] * inv);
  }
  *(half8*)(p + t * 8) = oa;
  *(half8*)(p + 2048 + t * 8) = ob;
}

// ---------------------------------------------------------------------------
// fused residual + f16 split-K slab reduce + (optional bias) + LayerNorm.
// One block per row, D=1024. b = base of nchunks f16 slabs, stride cs elems.
// ---------------------------------------------------------------------------
__global__ void add_ln(const float* __restrict__ a, const f16* __restrict__ b,
                       int nchunks, size_t cs, const float* __restrict__ bias,
                       const float* __restrict__ g, const float* __restrict__ be,
                       float* __restrict__ outf, f16* __restrict__ outh, int D) {
  const int row = blockIdx.x;
  const int t = threadIdx.x;
  const int lane = t & 63, wave = t >> 6;
  const float4 av = *(const float4*)(a + (size_t)row * D + t * 4);
  float s[4] = {av.x, av.y, av.z, av.w};
  for (int c = 0; c < nchunks; ++c) {
    const half4 bv = *(const half4*)(b + c * cs + (size_t)row * D + t * 4);
    s[0] += (float)bv[0]; s[1] += (float)bv[1];
    s[2] += (float)bv[2]; s[3] += (float)bv[3];
  }
  if (bias != nullptr) {
    const float4 bb = *(const float4*)(bias + t * 4);
    s[0] += bb.x; s[1] += bb.y; s[2] += bb.z; s[3] += bb.w;
  }
  float sum = s[0] + s[1] + s[2] + s[3];
  float sq = s[0] * s[0] + s[1] * s[1] + s[2] * s[2] + s[3] * s[3];
#pragma unroll
  for (int off = 32; off > 0; off >>= 1) {
    sum += __shfl_xor(sum, off);
    sq += __shfl_xor(sq, off);
  }
  __shared__ float red[8];
  if (lane == 0) {
    red[wave] = sum;
    red[4 + wave] = sq;
  }
  __syncthreads();
  sum = red[0] + red[1] + red[2] + red[3];
  sq = red[4] + red[5] + red[6] + red[7];
  const float mu = sum / (float)D;
  const float rv = rsqrtf(sq / (float)D - mu * mu + LN_EPS);
  const float4 gv = *(const float4*)(g + t * 4);
  const float4 bev = *(const float4*)(be + t * 4);
  float y0 = (s[0] - mu) * rv * gv.x + bev.x;
  float y1 = (s[1] - mu) * rv * gv.y + bev.y;
  float y2 = (s[2] - mu) * rv * gv.z + bev.z;
  float y3 = (s[3] - mu) * rv * gv.w + bev.w;
  if (outf != nullptr) {
    float4 o = {y0, y1, y2, y3};
    *(float4*)(outf + (size_t)row * D + t * 4) = o;
  }
  if (outh != nullptr) {
    f16* ob = outh + (size_t)row * D + t * 4;
    ob[0] = (f16)y0;
    ob[1] = (f16)y1;
    ob[2] = (f16)y2;
    ob[3] = (f16)y3;
  }
}

// ---------------------------------------------------------------------------
// launch
// ---------------------------------------------------------------------------
extern "C" void kernel_launch(void* const* d_in, const int* in_sizes, int n_in,
                              void* d_out, int out_size, void* d_ws,
                              size_t ws_size, hipStream_t stream) {
  constexpr int N = 4096, D = 1024, H = 4096;
  const float* x = (const float*)d_in[0];
  const float* Wq = (const float*)d_in[1];
  const float* Wk = (const float*)d_in[2];
  const float* Wv = (const float*)d_in[3];
  const float* Wo = (const float*)d_in[4];
  const float* W1 = (const float*)d_in[5];
  const float* b1 = (const float*)d_in[6];
  const float* W2 = (const float*)d_in[7];
  const float* b2 = (const float*)d_in[8];
  const float* g1 = (const float*)d_in[9];
  const float* be1 = (const float*)d_in[10];
  const float* g2 = (const float*)d_in[11];
  const float* be2 = (const float*)d_in[12];
  float* out = (float*)d_out;

  const size_t MB = 1024ull * 1024ull;
  char* w = (char*)d_ws;
  // workspace layout (228 MB used; hazard-checked reuse; offsets in MB):
  f16* xb   = (f16*)(w + 0 * MB);     // 8   [N,D]
  f16* Wqb  = (f16*)(w + 8 * MB);     // 8   [D,H]
  f16* Wkb  = (f16*)(w + 16 * MB);    // 8   [D,H]
  f16* Wvb  = (f16*)(w + 24 * MB);    // 8   [D,H]
  f16* WoT  = (f16*)(w + 32 * MB);    // 8   [D,H]
  f16* W1T  = (f16*)(w + 40 * MB);    // 8   [H,D]
  f16* W2T  = (f16*)(w + 48 * MB);    // 8   [D,H]
  f16* WqkT = (f16*)(w + 56 * MB);    // 2   [D,D] = (Wq@Wk^T)^T
  f16* WvoT = (f16*)(w + 58 * MB);    // 2   [D,D] = (Wv@Wo)^T
  f16* th   = (f16*)(w + 60 * MB);    // 8   [N,D]; dead after S
  f16* xvoT = (f16*)(w + 68 * MB);    // 8   [D,N]
  f16* F1   = (f16*)(w + 76 * MB);    // 32  [N,H]
  f16* Sh   = (f16*)(w + 108 * MB);   // 32  [N,N] f16; dead after softmax
  f16* parA = (f16*)(w + 108 * MB);   // 4x8MB f16 slabs (over dead Sh)
  f16* Pb   = (f16*)(w + 140 * MB);   // 32  [N,N]; dead after attn
  float* hf = (float*)(w + 172 * MB); // 16  [N,D]
  f16* hb   = (f16*)(w + 188 * MB);   // 8   [N,D]
  f16* parQK = (f16*)(w + 196 * MB);  // 16 = 8x2MB f16 slabs; dead after reduce
  f16* parVO = (f16*)(w + 212 * MB);  // 16 = 8x2MB f16 slabs; dead after reduce

  // ---- input prep: 4 converts + 3 transposes, ONE dispatch, vectorized ----
  prep_inputs<<<dim3(1024, 7), 256, 0, stream>>>(
      x, Wq, Wk, Wv, W1, Wo, W2, xb, Wqb, Wkb, Wvb, W1T, WoT, W2T);

  // ---- weight precomposition (both [D,D] composites, one dispatch) ----
  gemm_pre256<<<dim3(4, 4, 16), 512, 0, stream>>>(
      Wkb, Wqb, WoT, Wvb, parQK, parVO, D, H);
  reduce_dual<<<2 * (D * D) / 1024, 256, 0, stream>>>(parQK, parVO, WqkT,
                                                      WvoT, D * D);

  // ---- attention ----
  // th = xb@WqkT^T [N,D] and xvoT = WvoT@xb^T [D,N], one dispatch
  gemm_dual256<<<dim3(4, 32), 512, 0, stream>>>(xb, WqkT, WvoT, th, xvoT,
                                                N, D);
  // S = th @ xb^T  [N,N] f16 logits (K=1024), 256^2 8-phase kernel
  gemm_nt256<1><<<dim3(N / 256, N / 256, 1), 512, 0, stream>>>(
      th, xb, Sh, nullptr, N, N, D, D, D, N);
  softmax_rows<<<N, 256, 0, stream>>>(Sh, Pb, N);
  // attn partials = Pb @ xvoT^T  [N,D], split-K=4, f16 slabs (over dead Sh)
  gemm_nt256<1><<<dim3(D / 256, N / 256, 4), 512, 0, stream>>>(
      Pb, xvoT, parA, nullptr, N, D, N, N, N, D);
  // h = LN(x + sum(attn partials))
  add_ln<<<N, 256, 0, stream>>>(x, parA, 4, (size_t)N * D, nullptr, g1, be1,
                                hf, hb, D);

  // ---- feed-forward ----
  // F1 = relu(hb @ W1T^T + b1)  [N,H] f16
  gemm_nt256<2><<<dim3(H / 256, N / 256, 1), 512, 0, stream>>>(
      hb, W1T, F1, b1, N, H, D, D, D, H);
  // F2 partials = F1 @ W2T^T  [N,D], split-K=4, f16 slabs
  gemm_nt256<1><<<dim3(D / 256, N / 256, 4), 512, 0, stream>>>(
      F1, W2T, parA, nullptr, N, D, H, H, H, D);
  // out = LN(hf + sum(F2 partials) + b2)
  add_ln<<<N, 256, 0, stream>>>(hf, parA, 4, (size_t)N * D, b2, g2, be2,
                                out, nullptr, D);
}